// Round 1
// baseline (1040.846 us; speedup 1.0000x reference)
//
#include <hip/hip_runtime.h>

// ---------------------------------------------------------------------------
// MultiMonotoneHollowConv: Z = -( (A^T A - blockdiag) x - (b/||b||) g )
//
// Folded form (derived; pads are "full" so compositions never clip):
//   out0 = -( G00(5x5) * x0  +  D[phase] . x0  +  T10^T(Y1)  - b0*g0/||b0|| )
//   out1 = -( T11^T(Y1)      -  sub1[group] . x1            - b1*g1/||b1|| )
//   Y1   = conv(x0, W10, s=2, p=3) + conv(x1, W11, s=1, p=2)   (B,32,130,130)
// where D[p] = -(G00 center + G10 center[p])  implements the "hollow" diag
// subtraction for Z0, and sub1 the group-block-diag for Z1.
// ---------------------------------------------------------------------------

#define B_ 16

// workspace layout (floats)
static constexpr int Y1_ELEMS  = B_ * 32 * 130 * 130;       // 8,652,800
static constexpr int OFF_G00   = Y1_ELEMS;                  // 6400 : [dd][n][m]
static constexpr int OFF_D     = OFF_G00 + 6400;            // 1024 : [p][n][m]
static constexpr int OFF_SUB1  = OFF_D + 1024;              // 512  : [g*16+n][m]
static constexpr int OFF_SUMS  = OFF_SUB1 + 512;            // 2

// ---------------------------------------------------------------------------
__global__ void precompute_k(const float* __restrict__ W00,
                             const float* __restrict__ W10,
                             const float* __restrict__ W11,
                             float* __restrict__ ws) {
  int tid = threadIdx.x;
  float* g00  = ws + OFF_G00;
  float* Dm   = ws + OFF_D;
  float* sub1 = ws + OFF_SUB1;
  float* sums = ws + OFF_SUMS;
  if (tid < 2) sums[tid] = 0.f;

  // G00[m,n,dy,dx] = sum_o sum_a W00[o,m,a] W00[o,n,a+d]
  for (int e = tid; e < 6400; e += blockDim.x) {
    int m = e & 15, n = (e >> 4) & 15, dd = e >> 8;
    int dy = dd / 5 - 2, dx = dd % 5 - 2;
    float s = 0.f;
    for (int o = 0; o < 16; ++o) {
      const float* wm = W00 + (o * 16 + m) * 9;
      const float* wn = W00 + (o * 16 + n) * 9;
      for (int ay = 0; ay < 3; ++ay) {
        int ay2 = ay + dy; if (ay2 < 0 || ay2 > 2) continue;
        for (int ax = 0; ax < 3; ++ax) {
          int ax2 = ax + dx; if (ax2 < 0 || ax2 > 2) continue;
          s += wm[ay * 3 + ax] * wn[ay2 * 3 + ax2];
        }
      }
    }
    g00[dd * 256 + n * 16 + m] = s;
  }

  // D[py,px,n,m] = -(G00 center + G10 center at phase)
  // phase sets per dim: py==0 -> b in {1};  py==1 -> b in {0,2}
  for (int e = tid; e < 1024; e += blockDim.x) {
    int m = e & 15, n = (e >> 4) & 15, px = (e >> 8) & 1, py = (e >> 9) & 1;
    float c0 = 0.f;
    for (int o = 0; o < 16; ++o) {
      const float* wm = W00 + (o * 16 + m) * 9;
      const float* wn = W00 + (o * 16 + n) * 9;
      for (int t = 0; t < 9; ++t) c0 += wm[t] * wn[t];
    }
    float c1 = 0.f;
    for (int o = 0; o < 32; ++o) {
      const float* wm = W10 + (o * 16 + m) * 9;
      const float* wn = W10 + (o * 16 + n) * 9;
      for (int by = 0; by < 3; ++by) {
        if ((py == 0) ? (by != 1) : (by == 1)) continue;
        for (int bx = 0; bx < 3; ++bx) {
          if ((px == 0) ? (bx != 1) : (bx == 1)) continue;
          c1 += wm[by * 3 + bx] * wn[by * 3 + bx];
        }
      }
    }
    Dm[(py * 2 + px) * 256 + n * 16 + m] = -c0 - c1;
  }

  // sub1[g,n,m] = sum_o sum_t W11[o,g*16+m,t] W11[o,g*16+n,t]  (symmetric)
  for (int e = tid; e < 512; e += blockDim.x) {
    int m = e & 15, n = (e >> 4) & 15, g = e >> 8;
    float s = 0.f;
    for (int o = 0; o < 32; ++o) {
      const float* wm = W11 + (o * 32 + g * 16 + m) * 9;
      const float* wn = W11 + (o * 32 + g * 16 + n) * 9;
      for (int t = 0; t < 9; ++t) s += wm[t] * wn[t];
    }
    sub1[(g * 16 + n) * 16 + m] = s;
  }
}

// ---------------------------------------------------------------------------
__global__ void sumsq_k(const float* __restrict__ src, int n, float* __restrict__ dst) {
  float s = 0.f;
  for (int i = blockIdx.x * blockDim.x + threadIdx.x; i < n; i += gridDim.x * blockDim.x) {
    float v = src[i];
    s += v * v;
  }
  #pragma unroll
  for (int off = 32; off > 0; off >>= 1) s += __shfl_down(s, off, 64);
  if ((threadIdx.x & 63) == 0) atomicAdd(dst, s);
}

// ---------------------------------------------------------------------------
// Y1[b,o,iy,ix] = sum_{c,b'} W10[o,c,b'] x0[b,c,2iy+by-3,2ix+bx-3]
//              + sum_{c,a }  W11[o,c,a ] x1[b,c, iy+ay-2, ix+ax-2]
__global__ __launch_bounds__(256) void y1_kernel(const float* __restrict__ x0,
                                                 const float* __restrict__ x1,
                                                 const float* __restrict__ W10,
                                                 const float* __restrict__ W11,
                                                 float* __restrict__ ws) {
  __shared__ float w10s[9 * 16 * 32];  // [t][c][o]
  __shared__ float w11s[9 * 32 * 32];  // [t][c][o]
  for (int e = threadIdx.x; e < 4608; e += 256) {
    int o = e & 31, c = (e >> 5) & 15, t = e >> 9;
    w10s[e] = W10[(o * 16 + c) * 9 + t];
  }
  for (int e = threadIdx.x; e < 9216; e += 256) {
    int o = e & 31, c = (e >> 5) & 31, t = e >> 10;
    w11s[e] = W11[(o * 32 + c) * 9 + t];
  }
  __syncthreads();

  int t = blockIdx.x * 256 + threadIdx.x;
  if (t >= B_ * 130 * 130) return;
  int ix = t % 130;
  int r  = t / 130;
  int iy = r % 130;
  int b  = r / 130;

  float acc[32];
  #pragma unroll
  for (int i = 0; i < 32; ++i) acc[i] = 0.f;

  const float* x0b = x0 + b * (16 * 65536);
  for (int tap = 0; tap < 9; ++tap) {
    int by = tap / 3, bx = tap % 3;
    int ys = 2 * iy + by - 3, xs = 2 * ix + bx - 3;
    if ((unsigned)ys < 256u && (unsigned)xs < 256u) {
      const float* xp = x0b + ys * 256 + xs;
      const float4* wb = (const float4*)(w10s + tap * 512);
      #pragma unroll
      for (int c = 0; c < 16; ++c) {
        float v = xp[c * 65536];
        #pragma unroll
        for (int q = 0; q < 8; ++q) {
          float4 w = wb[c * 8 + q];
          acc[4 * q + 0] += w.x * v;
          acc[4 * q + 1] += w.y * v;
          acc[4 * q + 2] += w.z * v;
          acc[4 * q + 3] += w.w * v;
        }
      }
    }
  }

  const float* x1b = x1 + b * (32 * 16384);
  for (int tap = 0; tap < 9; ++tap) {
    int ay = tap / 3, ax = tap % 3;
    int ys = iy + ay - 2, xs = ix + ax - 2;
    if ((unsigned)ys < 128u && (unsigned)xs < 128u) {
      const float* xp = x1b + ys * 128 + xs;
      const float4* wb = (const float4*)(w11s + tap * 1024);
      #pragma unroll
      for (int c = 0; c < 32; ++c) {
        float v = xp[c * 16384];
        #pragma unroll
        for (int q = 0; q < 8; ++q) {
          float4 w = wb[c * 8 + q];
          acc[4 * q + 0] += w.x * v;
          acc[4 * q + 1] += w.y * v;
          acc[4 * q + 2] += w.z * v;
          acc[4 * q + 3] += w.w * v;
        }
      }
    }
  }

  float* yp = ws + b * 540800 + iy * 130 + ix;
  #pragma unroll
  for (int o = 0; o < 32; ++o) yp[o * 16900] = acc[o];
}

// ---------------------------------------------------------------------------
// out0[b,m,jy,jx] = -( sum_{n,d} G00[m,n,d] x0[n,j+d]
//                   +  sum_n D[p][n,m] x0[n,j]
//                   +  sum_{o,taps} W10[o,m,b] Y1[o, (j+3-b)/2]
//                   -  b0[m,j] * g0/||b0|| )
__global__ __launch_bounds__(256) void out0_kernel(const float* __restrict__ x0,
                                                   const float* __restrict__ b0,
                                                   const float* __restrict__ g,
                                                   const float* __restrict__ W10,
                                                   const float* __restrict__ ws,
                                                   float* __restrict__ out) {
  __shared__ float g00s[6400];   // [dd][n][m]
  __shared__ float dms[1024];    // [p][n][m]
  __shared__ float w10s[4608];   // [t][o][m]
  for (int e = threadIdx.x; e < 6400; e += 256) g00s[e] = ws[OFF_G00 + e];
  for (int e = threadIdx.x; e < 1024; e += 256) dms[e] = ws[OFF_D + e];
  for (int e = threadIdx.x; e < 4608; e += 256) {
    int m = e & 15, o = (e >> 4) & 31, t = e >> 9;
    w10s[e] = W10[(o * 16 + m) * 9 + t];
  }
  __syncthreads();

  int t = blockIdx.x * 256 + threadIdx.x;  // exactly 16*256*256 threads
  int jx = t & 255, jy = (t >> 8) & 255, b = t >> 16;

  float acc[16];
  #pragma unroll
  for (int i = 0; i < 16; ++i) acc[i] = 0.f;

  const float* x0b = x0 + b * (16 * 65536);

  // 5x5 G00 conv (same-pad)
  for (int dy = -2; dy <= 2; ++dy) {
    int ys = jy + dy;
    if ((unsigned)ys >= 256u) continue;
    for (int dx = -2; dx <= 2; ++dx) {
      int xs = jx + dx;
      if ((unsigned)xs >= 256u) continue;
      const float* xp = x0b + ys * 256 + xs;
      const float4* gb = (const float4*)(g00s + ((dy + 2) * 5 + (dx + 2)) * 256);
      #pragma unroll
      for (int n = 0; n < 16; ++n) {
        float v = xp[n * 65536];
        #pragma unroll
        for (int q = 0; q < 4; ++q) {
          float4 w = gb[n * 4 + q];
          acc[4 * q + 0] += w.x * v;
          acc[4 * q + 1] += w.y * v;
          acc[4 * q + 2] += w.z * v;
          acc[4 * q + 3] += w.w * v;
        }
      }
    }
  }

  // hollow-diag pointwise correction, phase p
  {
    int p = ((jy & 1) << 1) | (jx & 1);
    const float* xp = x0b + jy * 256 + jx;
    const float4* db = (const float4*)(dms + p * 256);
    #pragma unroll
    for (int n = 0; n < 16; ++n) {
      float v = xp[n * 65536];
      #pragma unroll
      for (int q = 0; q < 4; ++q) {
        float4 w = db[n * 4 + q];
        acc[4 * q + 0] += w.x * v;
        acc[4 * q + 1] += w.y * v;
        acc[4 * q + 2] += w.z * v;
        acc[4 * q + 3] += w.w * v;
      }
    }
  }

  // T10^T(Y1): phase-dependent taps, indices always interior
  {
    int uy = jy >> 1, ux = jx >> 1;
    int niy, nix, iys[2], bys[2], ixs[2], bxs[2];
    if (jy & 1) { niy = 2; iys[0] = uy + 2; bys[0] = 0; iys[1] = uy + 1; bys[1] = 2; }
    else        { niy = 1; iys[0] = uy + 1; bys[0] = 1; }
    if (jx & 1) { nix = 2; ixs[0] = ux + 2; bxs[0] = 0; ixs[1] = ux + 1; bxs[1] = 2; }
    else        { nix = 1; ixs[0] = ux + 1; bxs[0] = 1; }
    const float* y1b = ws + b * 540800;
    for (int ti = 0; ti < niy; ++ti) {
      for (int tj = 0; tj < nix; ++tj) {
        const float* yp = y1b + iys[ti] * 130 + ixs[tj];
        const float4* wb = (const float4*)(w10s + (bys[ti] * 3 + bxs[tj]) * 512);
        #pragma unroll
        for (int o = 0; o < 32; ++o) {
          float v = yp[o * 16900];
          #pragma unroll
          for (int q = 0; q < 4; ++q) {
            float4 w = wb[o * 4 + q];
            acc[4 * q + 0] += w.x * v;
            acc[4 * q + 1] += w.y * v;
            acc[4 * q + 2] += w.z * v;
            acc[4 * q + 3] += w.w * v;
          }
        }
      }
    }
  }

  float rs0 = g[0] / sqrtf(ws[OFF_SUMS]);
  const float* bp = b0 + jy * 256 + jx;
  float* op = out + b * (16 * 65536) + jy * 256 + jx;
  #pragma unroll
  for (int m = 0; m < 16; ++m) {
    float zv = acc[m] - bp[m * 65536] * rs0;
    op[m * 65536] = -zv;
  }
}

// ---------------------------------------------------------------------------
// out1[b,c,jy,jx] = -( sum_{o,a} W11[o,c,a] Y1[o, j+2-a]
//                   -  sum_n sub1[g,n,m] x1[g*16+n, j]
//                   -  b1[c,j] * g1/||b1|| )
__global__ __launch_bounds__(256) void out1_kernel(const float* __restrict__ x1,
                                                   const float* __restrict__ b1,
                                                   const float* __restrict__ g,
                                                   const float* __restrict__ W11,
                                                   const float* __restrict__ ws,
                                                   float* __restrict__ out) {
  __shared__ float w11s[9216];  // [t][o][c]
  __shared__ float sub1s[512];
  for (int e = threadIdx.x; e < 9216; e += 256) {
    int c = e & 31, o = (e >> 5) & 31, t = e >> 10;
    w11s[e] = W11[(o * 32 + c) * 9 + t];
  }
  for (int e = threadIdx.x; e < 512; e += 256) sub1s[e] = ws[OFF_SUB1 + e];
  __syncthreads();

  int t = blockIdx.x * 256 + threadIdx.x;  // exactly 16*128*128 threads
  int jx = t & 127, jy = (t >> 7) & 127, b = t >> 14;

  float acc[32];
  #pragma unroll
  for (int i = 0; i < 32; ++i) acc[i] = 0.f;

  const float* y1b = ws + b * 540800;
  for (int tap = 0; tap < 9; ++tap) {
    int ay = tap / 3, ax = tap % 3;
    const float* yp = y1b + (jy + 2 - ay) * 130 + (jx + 2 - ax);  // always in range
    const float4* wb = (const float4*)(w11s + tap * 1024);
    #pragma unroll
    for (int o = 0; o < 32; ++o) {
      float v = yp[o * 16900];
      #pragma unroll
      for (int q = 0; q < 8; ++q) {
        float4 w = wb[o * 8 + q];
        acc[4 * q + 0] += w.x * v;
        acc[4 * q + 1] += w.y * v;
        acc[4 * q + 2] += w.z * v;
        acc[4 * q + 3] += w.w * v;
      }
    }
  }

  // group-block-diag pointwise subtraction
  const float* x1b = x1 + b * (32 * 16384) + jy * 128 + jx;
  #pragma unroll
  for (int gg = 0; gg < 2; ++gg) {
    #pragma unroll
    for (int n = 0; n < 16; ++n) {
      float v = x1b[(gg * 16 + n) * 16384];
      const float4* sb = (const float4*)(sub1s + (gg * 16 + n) * 16);
      #pragma unroll
      for (int q = 0; q < 4; ++q) {
        float4 w = sb[q];
        acc[gg * 16 + 4 * q + 0] -= w.x * v;
        acc[gg * 16 + 4 * q + 1] -= w.y * v;
        acc[gg * 16 + 4 * q + 2] -= w.z * v;
        acc[gg * 16 + 4 * q + 3] -= w.w * v;
      }
    }
  }

  float rs1 = g[1] / sqrtf(ws[OFF_SUMS + 1]);
  const float* bp = b1 + jy * 128 + jx;
  float* op = out + 16777216 + b * (32 * 16384) + jy * 128 + jx;
  #pragma unroll
  for (int c = 0; c < 32; ++c) {
    float zv = acc[c] - bp[c * 16384] * rs1;
    op[c * 16384] = -zv;
  }
}

// ---------------------------------------------------------------------------
extern "C" void kernel_launch(void* const* d_in, const int* in_sizes, int n_in,
                              void* d_out, int out_size, void* d_ws, size_t ws_size,
                              hipStream_t stream) {
  const float* x0  = (const float*)d_in[0];
  const float* x1  = (const float*)d_in[1];
  const float* W00 = (const float*)d_in[2];
  const float* W10 = (const float*)d_in[3];
  const float* W11 = (const float*)d_in[4];
  const float* b0  = (const float*)d_in[5];
  const float* b1  = (const float*)d_in[6];
  const float* g   = (const float*)d_in[7];
  float* out = (float*)d_out;
  float* ws  = (float*)d_ws;

  precompute_k<<<1, 256, 0, stream>>>(W00, W10, W11, ws);
  sumsq_k<<<512, 256, 0, stream>>>(b0, 16 * 256 * 256, ws + OFF_SUMS);
  sumsq_k<<<512, 256, 0, stream>>>(b1, 32 * 128 * 128, ws + OFF_SUMS + 1);
  y1_kernel<<<(B_ * 130 * 130 + 255) / 256, 256, 0, stream>>>(x0, x1, W10, W11, ws);
  out0_kernel<<<(B_ * 256 * 256) / 256, 256, 0, stream>>>(x0, b0, g, W10, ws, out);
  out1_kernel<<<(B_ * 128 * 128) / 256, 256, 0, stream>>>(x1, b1, g, W11, ws, out);
}

// Round 2
// 791.683 us; speedup vs baseline: 1.3147x; 1.3147x over previous
//
#include <hip/hip_runtime.h>

// ---------------------------------------------------------------------------
// MultiMonotoneHollowConv: Z = -( (A^T A - blockdiag) x - (b/||b||) g )
//
// Folded form (pads are "full" so compositions never clip):
//   out0 = -( G00(5x5)*x0 + D[phase].x0 + T10^T(Y1) - b0*g0/||b0|| )
//   out1 = -( T11^T(Y1) - sub1[group].x1 - b1*g1/||b1|| )
//   Y1   = conv(x0,W10,s2,p3) + conv(x1,W11,s1,p2)   (B,32,130,130)
//
// Round 2: register pixel-blocking (4 px/thread out0, 2 px/thread y1/out1),
// aligned vector loads, padded Y1 rows (132), parallel precompute.
// ---------------------------------------------------------------------------

#define B_ 16

// padded Y1: [b][o][iy][132], iy in [0,130)
static constexpr int Y1_RS    = 132;
static constexpr int Y1_PL    = 130 * 132;      // 17160
static constexpr int Y1_BS    = 32 * Y1_PL;     // 549120
static constexpr int Y1_ELEMS = B_ * Y1_BS;     // 8,785,920
static constexpr int OFF_G00  = Y1_ELEMS;       // 6400 : [dd][n][m]
static constexpr int OFF_D    = OFF_G00 + 6400; // 1024 : [p][n][m]
static constexpr int OFF_SUB1 = OFF_D + 1024;   // 512  : [g*16+n][m]
static constexpr int OFF_SUMS = OFF_SUB1 + 512; // 2

__device__ __forceinline__ void fma4(float4& a, float w, const float4& x) {
  a.x = fmaf(w, x.x, a.x); a.y = fmaf(w, x.y, a.y);
  a.z = fmaf(w, x.z, a.z); a.w = fmaf(w, x.w, a.w);
}
// even/odd phase weights across the 4 px
__device__ __forceinline__ void fma4p(float4& a, float we, float wo, const float4& x) {
  a.x = fmaf(we, x.x, a.x); a.y = fmaf(wo, x.y, a.y);
  a.z = fmaf(we, x.z, a.z); a.w = fmaf(wo, x.w, a.w);
}
// T10^T per-m contribution to the 4 px (jx0 even):
//  px0 += w1*y1 ; px1 += w0*y2 + w2*y1 ; px2 += w1*y2 ; px3 += w0*y3 + w2*y2
__device__ __forceinline__ void t10m(float4& a, float w0, float w1, float w2,
                                     float y1v, float y2v, float y3v) {
  a.x = fmaf(w1, y1v, a.x);
  a.y = fmaf(w0, y2v, fmaf(w2, y1v, a.y));
  a.z = fmaf(w1, y2v, a.z);
  a.w = fmaf(w0, y3v, fmaf(w2, y2v, a.w));
}

// ---------------------------------------------------------------------------
__global__ void precompute_k(const float* __restrict__ W00,
                             const float* __restrict__ W10,
                             const float* __restrict__ W11,
                             float* __restrict__ ws) {
  int gid = blockIdx.x * blockDim.x + threadIdx.x;
  int stride = gridDim.x * blockDim.x;
  float* g00  = ws + OFF_G00;
  float* Dm   = ws + OFF_D;
  float* sub1 = ws + OFF_SUB1;
  float* sums = ws + OFF_SUMS;
  if (gid < 2) sums[gid] = 0.f;

  // G00[m,n,dy,dx] = sum_o sum_a W00[o,m,a] W00[o,n,a+d]
  for (int e = gid; e < 6400; e += stride) {
    int m = e & 15, n = (e >> 4) & 15, dd = e >> 8;
    int dy = dd / 5 - 2, dx = dd % 5 - 2;
    float s = 0.f;
    for (int o = 0; o < 16; ++o) {
      const float* wm = W00 + (o * 16 + m) * 9;
      const float* wn = W00 + (o * 16 + n) * 9;
      for (int ay = 0; ay < 3; ++ay) {
        int ay2 = ay + dy; if (ay2 < 0 || ay2 > 2) continue;
        for (int ax = 0; ax < 3; ++ax) {
          int ax2 = ax + dx; if (ax2 < 0 || ax2 > 2) continue;
          s += wm[ay * 3 + ax] * wn[ay2 * 3 + ax2];
        }
      }
    }
    g00[dd * 256 + n * 16 + m] = s;
  }

  // D[py,px,n,m] = -(G00 center + G10 center at phase)
  for (int e = gid; e < 1024; e += stride) {
    int m = e & 15, n = (e >> 4) & 15, px = (e >> 8) & 1, py = (e >> 9) & 1;
    float c0 = 0.f;
    for (int o = 0; o < 16; ++o) {
      const float* wm = W00 + (o * 16 + m) * 9;
      const float* wn = W00 + (o * 16 + n) * 9;
      for (int t = 0; t < 9; ++t) c0 += wm[t] * wn[t];
    }
    float c1 = 0.f;
    for (int o = 0; o < 32; ++o) {
      const float* wm = W10 + (o * 16 + m) * 9;
      const float* wn = W10 + (o * 16 + n) * 9;
      for (int by = 0; by < 3; ++by) {
        if ((py == 0) ? (by != 1) : (by == 1)) continue;
        for (int bx = 0; bx < 3; ++bx) {
          if ((px == 0) ? (bx != 1) : (bx == 1)) continue;
          c1 += wm[by * 3 + bx] * wn[by * 3 + bx];
        }
      }
    }
    Dm[(py * 2 + px) * 256 + n * 16 + m] = -c0 - c1;
  }

  // sub1[g,n,m]
  for (int e = gid; e < 512; e += stride) {
    int m = e & 15, n = (e >> 4) & 15, g = e >> 8;
    float s = 0.f;
    for (int o = 0; o < 32; ++o) {
      const float* wm = W11 + (o * 32 + g * 16 + m) * 9;
      const float* wn = W11 + (o * 32 + g * 16 + n) * 9;
      for (int t = 0; t < 9; ++t) s += wm[t] * wn[t];
    }
    sub1[(g * 16 + n) * 16 + m] = s;
  }
}

// ---------------------------------------------------------------------------
__global__ void sumsq_k(const float* __restrict__ src, int n, float* __restrict__ dst) {
  float s = 0.f;
  for (int i = blockIdx.x * blockDim.x + threadIdx.x; i < n; i += gridDim.x * blockDim.x) {
    float v = src[i];
    s += v * v;
  }
  #pragma unroll
  for (int off = 32; off > 0; off >>= 1) s += __shfl_down(s, off, 64);
  if ((threadIdx.x & 63) == 0) atomicAdd(dst, s);
}

// ---------------------------------------------------------------------------
// Y1: 2 px along ix per thread.
__global__ __launch_bounds__(512) void y1_kernel(const float* __restrict__ x0,
                                                 const float* __restrict__ x1,
                                                 const float* __restrict__ W10,
                                                 const float* __restrict__ W11,
                                                 float* __restrict__ ws) {
  __shared__ float w10s[4608];  // [t][c][o]
  __shared__ float w11s[9216];  // [t][c][o]
  for (int e = threadIdx.x; e < 4608; e += 512) {
    int o = e & 31, c = (e >> 5) & 15, t = e >> 9;
    w10s[e] = W10[(o * 16 + c) * 9 + t];
  }
  for (int e = threadIdx.x; e < 9216; e += 512) {
    int o = e & 31, c = (e >> 5) & 31, t = e >> 10;
    w11s[e] = W11[(o * 32 + c) * 9 + t];
  }
  __syncthreads();

  int t = blockIdx.x * 512 + threadIdx.x;
  if (t >= B_ * 130 * 65) return;
  int ix0 = 2 * (t % 65);
  int r_  = t / 65;
  int iy  = r_ % 130;
  int b   = r_ / 130;

  float2 acc[32];
  #pragma unroll
  for (int i = 0; i < 32; ++i) acc[i] = make_float2(0.f, 0.f);

  // --- W10 path: xs = 2*ix + bx - 3; px pair uses r[bx], r[bx+2]
  const float* x0b = x0 + b * 1048576;
  int xbase = 2 * ix0 - 3;
  bool innerA = (xbase >= 0) && (xbase + 4 < 256);
  for (int by = 0; by < 3; ++by) {
    int ys = 2 * iy + by - 3;
    if ((unsigned)ys >= 256u) continue;
    const float* xrow = x0b + ys * 256;
    for (int c = 0; c < 16; ++c) {
      const float* xr = xrow + c * 65536 + xbase;
      float r[5];
      if (innerA) {
        #pragma unroll
        for (int k = 0; k < 5; ++k) r[k] = xr[k];
      } else {
        #pragma unroll
        for (int k = 0; k < 5; ++k) {
          int xx = xbase + k;
          r[k] = ((unsigned)xx < 256u) ? xrow[c * 65536 + xx] : 0.f;
        }
      }
      #pragma unroll
      for (int bx = 0; bx < 3; ++bx) {
        float xa = r[bx], xb = r[bx + 2];
        const float4* wb = (const float4*)(w10s + (by * 3 + bx) * 512 + c * 32);
        #pragma unroll
        for (int oq = 0; oq < 8; ++oq) {
          float4 w = wb[oq];
          acc[oq*4+0].x = fmaf(w.x, xa, acc[oq*4+0].x); acc[oq*4+0].y = fmaf(w.x, xb, acc[oq*4+0].y);
          acc[oq*4+1].x = fmaf(w.y, xa, acc[oq*4+1].x); acc[oq*4+1].y = fmaf(w.y, xb, acc[oq*4+1].y);
          acc[oq*4+2].x = fmaf(w.z, xa, acc[oq*4+2].x); acc[oq*4+2].y = fmaf(w.z, xb, acc[oq*4+2].y);
          acc[oq*4+3].x = fmaf(w.w, xa, acc[oq*4+3].x); acc[oq*4+3].y = fmaf(w.w, xb, acc[oq*4+3].y);
        }
      }
    }
  }

  // --- W11 path: xs = ix + ax - 2; px pair uses r[ax], r[ax+1]
  const float* x1b = x1 + b * 524288;
  int xb1 = ix0 - 2;
  bool innerB = (xb1 >= 0) && (xb1 + 3 < 128);
  for (int ay = 0; ay < 3; ++ay) {
    int ys = iy + ay - 2;
    if ((unsigned)ys >= 128u) continue;
    const float* xrow = x1b + ys * 128;
    for (int c = 0; c < 32; ++c) {
      const float* xr = xrow + c * 16384 + xb1;
      float r[4];
      if (innerB) {
        #pragma unroll
        for (int k = 0; k < 4; ++k) r[k] = xr[k];
      } else {
        #pragma unroll
        for (int k = 0; k < 4; ++k) {
          int xx = xb1 + k;
          r[k] = ((unsigned)xx < 128u) ? xrow[c * 16384 + xx] : 0.f;
        }
      }
      #pragma unroll
      for (int ax = 0; ax < 3; ++ax) {
        float xa = r[ax], xb = r[ax + 1];
        const float4* wb = (const float4*)(w11s + (ay * 3 + ax) * 1024 + c * 32);
        #pragma unroll
        for (int oq = 0; oq < 8; ++oq) {
          float4 w = wb[oq];
          acc[oq*4+0].x = fmaf(w.x, xa, acc[oq*4+0].x); acc[oq*4+0].y = fmaf(w.x, xb, acc[oq*4+0].y);
          acc[oq*4+1].x = fmaf(w.y, xa, acc[oq*4+1].x); acc[oq*4+1].y = fmaf(w.y, xb, acc[oq*4+1].y);
          acc[oq*4+2].x = fmaf(w.z, xa, acc[oq*4+2].x); acc[oq*4+2].y = fmaf(w.z, xb, acc[oq*4+2].y);
          acc[oq*4+3].x = fmaf(w.w, xa, acc[oq*4+3].x); acc[oq*4+3].y = fmaf(w.w, xb, acc[oq*4+3].y);
        }
      }
    }
  }

  float* yp = ws + b * Y1_BS + iy * Y1_RS + ix0;
  #pragma unroll
  for (int o = 0; o < 32; ++o) *(float2*)(yp + o * Y1_PL) = acc[o];
}

// ---------------------------------------------------------------------------
// out0: 4 px along jx per thread (jx0 = 4k).
__global__ __launch_bounds__(256) void out0_kernel(const float* __restrict__ x0,
                                                   const float* __restrict__ b0,
                                                   const float* __restrict__ g,
                                                   const float* __restrict__ W10,
                                                   const float* __restrict__ ws,
                                                   float* __restrict__ out) {
  __shared__ float g00s[6400];   // [dd][n][m]
  __shared__ float dms[1024];    // [p][n][m]
  __shared__ float w10s[4608];   // [t][o][m]
  for (int e = threadIdx.x; e < 6400; e += 256) g00s[e] = ws[OFF_G00 + e];
  for (int e = threadIdx.x; e < 1024; e += 256) dms[e] = ws[OFF_D + e];
  for (int e = threadIdx.x; e < 4608; e += 256) {
    int m = e & 15, o = (e >> 4) & 31, t = e >> 9;
    w10s[e] = W10[(o * 16 + m) * 9 + t];
  }
  __syncthreads();

  int t = blockIdx.x * 256 + threadIdx.x;  // 262144 threads
  int jx0 = (t & 63) << 2;
  int jy  = (t >> 6) & 255;
  int b   = t >> 14;

  float4 acc[16];
  #pragma unroll
  for (int i = 0; i < 16; ++i) acc[i] = make_float4(0.f, 0.f, 0.f, 0.f);

  const float* x0b = x0 + b * 1048576;

  // --- 5x5 G00 conv: 3 aligned quads per (row, n) cover all 5 dx windows
  for (int dyi = 0; dyi < 5; ++dyi) {
    int ys = jy + dyi - 2;
    if ((unsigned)ys >= 256u) continue;
    const float* xrow = x0b + ys * 256;
    const float* gb0 = g00s + dyi * 5 * 256;
    for (int n = 0; n < 16; ++n) {
      const float* xr = xrow + n * 65536;
      float r[12];
      if (jx0 >= 4) {
        float4 q = *(const float4*)(xr + jx0 - 4);
        r[0] = q.x; r[1] = q.y; r[2] = q.z; r[3] = q.w;
      } else { r[0] = r[1] = r[2] = r[3] = 0.f; }
      {
        float4 q = *(const float4*)(xr + jx0);
        r[4] = q.x; r[5] = q.y; r[6] = q.z; r[7] = q.w;
      }
      if (jx0 <= 248) {
        float4 q = *(const float4*)(xr + jx0 + 4);
        r[8] = q.x; r[9] = q.y; r[10] = q.z; r[11] = q.w;
      } else { r[8] = r[9] = r[10] = r[11] = 0.f; }
      #pragma unroll
      for (int dxi = 0; dxi < 5; ++dxi) {
        float4 xv = make_float4(r[2 + dxi], r[3 + dxi], r[4 + dxi], r[5 + dxi]);
        const float4* gb = (const float4*)(gb0 + dxi * 256 + n * 16);
        #pragma unroll
        for (int mq = 0; mq < 4; ++mq) {
          float4 w = gb[mq];
          fma4(acc[mq*4+0], w.x, xv);
          fma4(acc[mq*4+1], w.y, xv);
          fma4(acc[mq*4+2], w.z, xv);
          fma4(acc[mq*4+3], w.w, xv);
        }
      }
    }
  }

  // --- hollow-diag correction: phase alternates with jx parity
  {
    int pE = (jy & 1) << 1;
    const float4* dbe = (const float4*)(dms + pE * 256);
    const float4* dbo = (const float4*)(dms + (pE | 1) * 256);
    const float* xp = x0b + jy * 256 + jx0;
    for (int n = 0; n < 16; ++n) {
      float4 xv = *(const float4*)(xp + n * 65536);
      #pragma unroll
      for (int mq = 0; mq < 4; ++mq) {
        float4 we = dbe[n * 4 + mq], wo = dbo[n * 4 + mq];
        fma4p(acc[mq*4+0], we.x, wo.x, xv);
        fma4p(acc[mq*4+1], we.y, wo.y, xv);
        fma4p(acc[mq*4+2], we.z, wo.z, xv);
        fma4p(acc[mq*4+3], we.w, wo.w, xv);
      }
    }
  }

  // --- T10^T(Y1): rows phase-set by jy parity (wave-uniform), x handled in-reg
  {
    int uy = jy >> 1, ux = jx0 >> 1;
    const float* y1b = ws + b * Y1_BS;
    int niy, iys[2], tbs[2];
    if (jy & 1) { niy = 2; iys[0] = uy + 2; tbs[0] = 0; iys[1] = uy + 1; tbs[1] = 6; }
    else        { niy = 1; iys[0] = uy + 1; tbs[0] = 3; }
    for (int ti = 0; ti < niy; ++ti) {
      const float* yrow = y1b + iys[ti] * Y1_RS + ux;
      const float* w0b = w10s + (tbs[ti] + 0) * 512;
      const float* w1b = w10s + (tbs[ti] + 1) * 512;
      const float* w2b = w10s + (tbs[ti] + 2) * 512;
      for (int o = 0; o < 32; ++o) {
        const float* yo = yrow + o * Y1_PL;
        float2 p0 = *(const float2*)yo;
        float2 p1 = *(const float2*)(yo + 2);
        float y1v = p0.y, y2v = p1.x, y3v = p1.y;
        const float4* wq0 = (const float4*)(w0b + o * 16);
        const float4* wq1 = (const float4*)(w1b + o * 16);
        const float4* wq2 = (const float4*)(w2b + o * 16);
        #pragma unroll
        for (int mq = 0; mq < 4; ++mq) {
          float4 a0 = wq0[mq], a1 = wq1[mq], a2 = wq2[mq];
          t10m(acc[mq*4+0], a0.x, a1.x, a2.x, y1v, y2v, y3v);
          t10m(acc[mq*4+1], a0.y, a1.y, a2.y, y1v, y2v, y3v);
          t10m(acc[mq*4+2], a0.z, a1.z, a2.z, y1v, y2v, y3v);
          t10m(acc[mq*4+3], a0.w, a1.w, a2.w, y1v, y2v, y3v);
        }
      }
    }
  }

  float rs0 = g[0] / sqrtf(ws[OFF_SUMS]);
  const float* bp = b0 + jy * 256 + jx0;
  float* op = out + b * 1048576 + jy * 256 + jx0;
  #pragma unroll
  for (int m = 0; m < 16; ++m) {
    float4 bv = *(const float4*)(bp + m * 65536);
    float4 z;
    z.x = -(acc[m].x - bv.x * rs0);
    z.y = -(acc[m].y - bv.y * rs0);
    z.z = -(acc[m].z - bv.z * rs0);
    z.w = -(acc[m].w - bv.w * rs0);
    *(float4*)(op + m * 65536) = z;
  }
}

// ---------------------------------------------------------------------------
// out1: 2 px along jx per thread (jx0 = 2k).
__global__ __launch_bounds__(256) void out1_kernel(const float* __restrict__ x1,
                                                   const float* __restrict__ b1,
                                                   const float* __restrict__ g,
                                                   const float* __restrict__ W11,
                                                   const float* __restrict__ ws,
                                                   float* __restrict__ out) {
  __shared__ float w11s[9216];  // [t][o][c]
  __shared__ float sub1s[512];
  for (int e = threadIdx.x; e < 9216; e += 256) {
    int c = e & 31, o = (e >> 5) & 31, t = e >> 10;
    w11s[e] = W11[(o * 32 + c) * 9 + t];
  }
  for (int e = threadIdx.x; e < 512; e += 256) sub1s[e] = ws[OFF_SUB1 + e];
  __syncthreads();

  int t = blockIdx.x * 256 + threadIdx.x;  // 131072 threads
  int jx0 = (t & 63) << 1;
  int jy  = (t >> 6) & 127;
  int b   = t >> 13;

  float2 acc[32];
  #pragma unroll
  for (int i = 0; i < 32; ++i) acc[i] = make_float2(0.f, 0.f);

  const float* y1b = ws + b * Y1_BS;
  for (int ay = 0; ay < 3; ++ay) {
    const float* yrow = y1b + (jy + 2 - ay) * Y1_RS + jx0;  // rows always interior
    for (int o = 0; o < 32; ++o) {
      const float* yo = yrow + o * Y1_PL;
      float2 p0 = *(const float2*)yo;
      float2 p1 = *(const float2*)(yo + 2);
      float r[4] = { p0.x, p0.y, p1.x, p1.y };
      #pragma unroll
      for (int ax = 0; ax < 3; ++ax) {
        float ya = r[2 - ax], yb = r[3 - ax];
        const float4* wb = (const float4*)(w11s + (ay * 3 + ax) * 1024 + o * 32);
        #pragma unroll
        for (int cq = 0; cq < 8; ++cq) {
          float4 w = wb[cq];
          acc[cq*4+0].x = fmaf(w.x, ya, acc[cq*4+0].x); acc[cq*4+0].y = fmaf(w.x, yb, acc[cq*4+0].y);
          acc[cq*4+1].x = fmaf(w.y, ya, acc[cq*4+1].x); acc[cq*4+1].y = fmaf(w.y, yb, acc[cq*4+1].y);
          acc[cq*4+2].x = fmaf(w.z, ya, acc[cq*4+2].x); acc[cq*4+2].y = fmaf(w.z, yb, acc[cq*4+2].y);
          acc[cq*4+3].x = fmaf(w.w, ya, acc[cq*4+3].x); acc[cq*4+3].y = fmaf(w.w, yb, acc[cq*4+3].y);
        }
      }
    }
  }

  // group-block-diag subtraction
  const float* x1p = x1 + b * 524288 + jy * 128 + jx0;
  for (int n = 0; n < 32; ++n) {
    float2 xv = *(const float2*)(x1p + n * 16384);
    const float4* sb = (const float4*)(sub1s + n * 16);
    int base = n & 16;  // g*16
    #pragma unroll
    for (int mq = 0; mq < 4; ++mq) {
      float4 w = sb[mq];
      acc[base+mq*4+0].x -= w.x * xv.x; acc[base+mq*4+0].y -= w.x * xv.y;
      acc[base+mq*4+1].x -= w.y * xv.x; acc[base+mq*4+1].y -= w.y * xv.y;
      acc[base+mq*4+2].x -= w.z * xv.x; acc[base+mq*4+2].y -= w.z * xv.y;
      acc[base+mq*4+3].x -= w.w * xv.x; acc[base+mq*4+3].y -= w.w * xv.y;
    }
  }

  float rs1 = g[1] / sqrtf(ws[OFF_SUMS + 1]);
  const float* bp = b1 + jy * 128 + jx0;
  float* op = out + 16777216 + b * 524288 + jy * 128 + jx0;
  #pragma unroll
  for (int c = 0; c < 32; ++c) {
    float2 bv = *(const float2*)(bp + c * 16384);
    float2 z;
    z.x = -(acc[c].x - bv.x * rs1);
    z.y = -(acc[c].y - bv.y * rs1);
    *(float2*)(op + c * 16384) = z;
  }
}

// ---------------------------------------------------------------------------
extern "C" void kernel_launch(void* const* d_in, const int* in_sizes, int n_in,
                              void* d_out, int out_size, void* d_ws, size_t ws_size,
                              hipStream_t stream) {
  const float* x0  = (const float*)d_in[0];
  const float* x1  = (const float*)d_in[1];
  const float* W00 = (const float*)d_in[2];
  const float* W10 = (const float*)d_in[3];
  const float* W11 = (const float*)d_in[4];
  const float* b0  = (const float*)d_in[5];
  const float* b1  = (const float*)d_in[6];
  const float* g   = (const float*)d_in[7];
  float* out = (float*)d_out;
  float* ws  = (float*)d_ws;

  precompute_k<<<16, 256, 0, stream>>>(W00, W10, W11, ws);
  sumsq_k<<<512, 256, 0, stream>>>(b0, 16 * 256 * 256, ws + OFF_SUMS);
  sumsq_k<<<512, 256, 0, stream>>>(b1, 32 * 128 * 128, ws + OFF_SUMS + 1);
  y1_kernel<<<(B_ * 130 * 65 + 511) / 512, 512, 0, stream>>>(x0, x1, W10, W11, ws);
  out0_kernel<<<1024, 256, 0, stream>>>(x0, b0, g, W10, ws, out);
  out1_kernel<<<512, 256, 0, stream>>>(x1, b1, g, W11, ws, out);
}

// Round 3
// 672.428 us; speedup vs baseline: 1.5479x; 1.1773x over previous
//
#include <hip/hip_runtime.h>
#include <stdint.h>

// ---------------------------------------------------------------------------
// MultiMonotoneHollowConv, round 3: MFMA (bf16) for out0/out1.
//   out0 = -( G00(5x5,center->-G10c[phase]) * x0  +  T10^T(Y1)  - b0^*g0 )
//   out1 = -( W11^T(3x3) * Y1  -  sub1_blockdiag * x1  - b1^*g1 )
//   Y1   = conv(x0,W10,s2,p3) + conv(x1,W11,s1,p2)  (VALU fp32, stores bf16)
// MFMA frag layouts (gfx950, HW-verified per guide):
//   A[m=lane&15][k=quad*8+j], B[k=quad*8+j][n=lane&15], D: row m=quad*4+reg,
//   col n=lane&15.  K-chunks use ch-octet LDS planes so each B-frag is one
//   conflict-free ds_read_b128.
// ---------------------------------------------------------------------------

using short8 = __attribute__((ext_vector_type(8))) short;
using f32x4  = __attribute__((ext_vector_type(4))) float;

#define B_ 16

// workspace byte offsets (total ~34.38 MB; must stay < ~35.1 MB proven safe)
static constexpr size_t Y1T_OFF  = 0;                        // [16][130][132][32] bf16
static constexpr size_t Y1T_ROWB = 132 * 64;                 // 8448 B per (b,iy) row
static constexpr size_t X1T_OFF  = (size_t)16 * 130 * 132 * 64;        // 17,556,480
static constexpr size_t AB0_OFF  = X1T_OFF + (size_t)16 * 128 * 128 * 64; // +16,777,216
static constexpr size_t AB1_OFF  = AB0_OFF + 24 * 1024;     // blob0: 24 chunks
static constexpr size_t SUM_OFF  = AB1_OFF + 20 * 1024;     // blob1: 10 chunks x 2

__device__ __forceinline__ uint32_t bf16rne(float v) {
  uint32_t u = __float_as_uint(v);
  return (u + 0x7fffu + ((u >> 16) & 1u)) >> 16;
}
__device__ __forceinline__ uint32_t packbf(float lo, float hi) {
  return bf16rne(lo) | (bf16rne(hi) << 16);
}
__device__ __forceinline__ f32x4 mfma16(short8 a, short8 b, f32x4 c) {
  return __builtin_amdgcn_mfma_f32_16x16x32_bf16(a, b, c, 0, 0, 0);
}

// ---------------------------------------------------------------------------
// Weight blobs in exact A-fragment order (bf16), plus zero the norm sums.
// blob0 (out0): [0..12] G00 tap-pairs (k=tap_sub*16+ch), center tap zeroed;
//               [13..21] W10t taps (k=o);  [22,23] -G10c parity chunks (py=0,1;
//               k<16 even-px rows, k>=16 odd-px rows).
// blob1 (out1): [t=0..8][h=0,1] W11 taps (k=o, m=h*16+..); [9][h] -sub1 blockdiag.
__global__ void blob_k(const float* __restrict__ W00, const float* __restrict__ W10,
                       const float* __restrict__ W11, char* __restrict__ ws) {
  int e = blockIdx.x * 256 + threadIdx.x;
  if (e < 2) ((float*)(ws + SUM_OFF))[e] = 0.f;
  if (e < 12288) {
    int chunk = e >> 9, le = e & 511, lane = le >> 3, j = le & 7;
    int q = lane >> 4, m = lane & 15;
    float val = 0.f;
    if (chunk < 13) {
      int t = 2 * chunk + (q >> 1);
      int n = ((q & 1) << 3) + j;
      if (t <= 24 && t != 12) {
        int dy = t / 5 - 2, dx = t % 5 - 2;
        for (int o = 0; o < 16; ++o) {
          const float* wm = W00 + (o * 16 + m) * 9;
          const float* wn = W00 + (o * 16 + n) * 9;
          for (int ay = 0; ay < 3; ++ay) {
            int ay2 = ay + dy; if ((unsigned)ay2 > 2u) continue;
            for (int ax = 0; ax < 3; ++ax) {
              int ax2 = ax + dx; if ((unsigned)ax2 > 2u) continue;
              val += wm[ay * 3 + ax] * wn[ay2 * 3 + ax2];
            }
          }
        }
      }
    } else if (chunk < 22) {
      int tap = chunk - 13;
      int o = ((lane >> 4) << 3) + j;      // k = q*8+j
      val = W10[(o * 16 + m) * 9 + tap];
    } else {
      int py = chunk - 22;
      int k = ((lane >> 4) << 3) + j;
      int par = k >> 4, n = k & 15;
      for (int o = 0; o < 32; ++o) {
        const float* wn = W10 + (o * 16 + n) * 9;
        const float* wm = W10 + (o * 16 + m) * 9;
        for (int by = 0; by < 3; ++by) {
          if ((py == 0) ? (by != 1) : (by == 1)) continue;
          for (int bx = 0; bx < 3; ++bx) {
            if ((par == 0) ? (bx != 1) : (bx == 1)) continue;
            val -= wn[by * 3 + bx] * wm[by * 3 + bx];
          }
        }
      }
    }
    ((uint16_t*)(ws + AB0_OFF))[chunk * 512 + lane * 8 + j] = (uint16_t)bf16rne(val);
  } else if (e < 12288 + 10240) {
    int e2 = e - 12288;
    int chunk = e2 >> 10, r = e2 & 1023, h = r >> 9, le = r & 511;
    int lane = le >> 3, j = le & 7;
    int m = h * 16 + (lane & 15);
    int kk = ((lane >> 4) << 3) + j;      // k = q*8+j
    float val = 0.f;
    if (chunk < 9) {
      val = W11[(kk * 32 + m) * 9 + chunk];      // o = kk, tap = chunk
    } else if ((kk >> 4) == h) {
      int np = kk & 15;
      float s = 0.f;
      for (int o = 0; o < 32; ++o)
        for (int t = 0; t < 9; ++t)
          s += W11[(o * 32 + m) * 9 + t] * W11[(o * 32 + h * 16 + np) * 9 + t];
      val = -s;
    }
    ((uint16_t*)(ws + AB1_OFF))[(chunk * 2 + h) * 512 + lane * 8 + j] = (uint16_t)bf16rne(val);
  }
}

// ---------------------------------------------------------------------------
__global__ void sumsq_k(const float* __restrict__ src, int n, float* __restrict__ dst) {
  float s = 0.f;
  for (int i = blockIdx.x * blockDim.x + threadIdx.x; i < n; i += gridDim.x * blockDim.x) {
    float v = src[i];
    s += v * v;
  }
  #pragma unroll
  for (int off = 32; off > 0; off >>= 1) s += __shfl_down(s, off, 64);
  if ((threadIdx.x & 63) == 0) atomicAdd(dst, s);
}

// ---------------------------------------------------------------------------
// x1t[b][r][c][ch] = bf16(x1[b][ch][r][c])
__global__ __launch_bounds__(256) void x1t_k(const float* __restrict__ x1, char* __restrict__ ws) {
  __shared__ __align__(16) uint16_t tmp[128 * 32];
  int b = blockIdx.x >> 7, r = blockIdx.x & 127;
  int tid = threadIdx.x;
  for (int e = tid; e < 4096; e += 256) {
    int ch = e >> 7, c = e & 127;
    float v = x1[((size_t)(b * 32 + ch) * 128 + r) * 128 + c];
    tmp[c * 32 + ch] = (uint16_t)bf16rne(v);
  }
  __syncthreads();
  char* dst = ws + X1T_OFF + ((size_t)(b * 128 + r) * 128) * 64;
  for (int e = tid; e < 512; e += 256)
    *(short8*)(dst + e * 16) = *(const short8*)((const char*)tmp + e * 16);
}

// ---------------------------------------------------------------------------
// Y1 (VALU fp32, verified round-2 math), output packed bf16 [b][iy][ix][ch].
__global__ __launch_bounds__(512) void y1_kernel(const float* __restrict__ x0,
                                                 const float* __restrict__ x1,
                                                 const float* __restrict__ W10,
                                                 const float* __restrict__ W11,
                                                 char* __restrict__ ws) {
  __shared__ float w10s[4608];  // [t][c][o]
  __shared__ float w11s[9216];  // [t][c][o]
  for (int e = threadIdx.x; e < 4608; e += 512) {
    int o = e & 31, c = (e >> 5) & 15, t = e >> 9;
    w10s[e] = W10[(o * 16 + c) * 9 + t];
  }
  for (int e = threadIdx.x; e < 9216; e += 512) {
    int o = e & 31, c = (e >> 5) & 31, t = e >> 10;
    w11s[e] = W11[(o * 32 + c) * 9 + t];
  }
  __syncthreads();

  int t = blockIdx.x * 512 + threadIdx.x;
  if (t >= B_ * 130 * 65) return;
  int ix0 = 2 * (t % 65);
  int r_  = t / 65;
  int iy  = r_ % 130;
  int b   = r_ / 130;

  float2 acc[32];
  #pragma unroll
  for (int i = 0; i < 32; ++i) acc[i] = make_float2(0.f, 0.f);

  const float* x0b = x0 + (size_t)b * 1048576;
  int xbase = 2 * ix0 - 3;
  bool innerA = (xbase >= 0) && (xbase + 4 < 256);
  for (int by = 0; by < 3; ++by) {
    int ys = 2 * iy + by - 3;
    if ((unsigned)ys >= 256u) continue;
    const float* xrow = x0b + ys * 256;
    for (int c = 0; c < 16; ++c) {
      const float* xr = xrow + c * 65536 + xbase;
      float r[5];
      if (innerA) {
        #pragma unroll
        for (int k = 0; k < 5; ++k) r[k] = xr[k];
      } else {
        #pragma unroll
        for (int k = 0; k < 5; ++k) {
          int xx = xbase + k;
          r[k] = ((unsigned)xx < 256u) ? xrow[c * 65536 + xx] : 0.f;
        }
      }
      #pragma unroll
      for (int bx = 0; bx < 3; ++bx) {
        float xa = r[bx], xb = r[bx + 2];
        const float4* wb = (const float4*)(w10s + (by * 3 + bx) * 512 + c * 32);
        #pragma unroll
        for (int oq = 0; oq < 8; ++oq) {
          float4 w = wb[oq];
          acc[oq*4+0].x = fmaf(w.x, xa, acc[oq*4+0].x); acc[oq*4+0].y = fmaf(w.x, xb, acc[oq*4+0].y);
          acc[oq*4+1].x = fmaf(w.y, xa, acc[oq*4+1].x); acc[oq*4+1].y = fmaf(w.y, xb, acc[oq*4+1].y);
          acc[oq*4+2].x = fmaf(w.z, xa, acc[oq*4+2].x); acc[oq*4+2].y = fmaf(w.z, xb, acc[oq*4+2].y);
          acc[oq*4+3].x = fmaf(w.w, xa, acc[oq*4+3].x); acc[oq*4+3].y = fmaf(w.w, xb, acc[oq*4+3].y);
        }
      }
    }
  }

  const float* x1b = x1 + (size_t)b * 524288;
  int xb1 = ix0 - 2;
  bool innerB = (xb1 >= 0) && (xb1 + 3 < 128);
  for (int ay = 0; ay < 3; ++ay) {
    int ys = iy + ay - 2;
    if ((unsigned)ys >= 128u) continue;
    const float* xrow = x1b + ys * 128;
    for (int c = 0; c < 32; ++c) {
      const float* xr = xrow + c * 16384 + xb1;
      float r[4];
      if (innerB) {
        #pragma unroll
        for (int k = 0; k < 4; ++k) r[k] = xr[k];
      } else {
        #pragma unroll
        for (int k = 0; k < 4; ++k) {
          int xx = xb1 + k;
          r[k] = ((unsigned)xx < 128u) ? xrow[c * 16384 + xx] : 0.f;
        }
      }
      #pragma unroll
      for (int ax = 0; ax < 3; ++ax) {
        float xa = r[ax], xb = r[ax + 1];
        const float4* wb = (const float4*)(w11s + (ay * 3 + ax) * 1024 + c * 32);
        #pragma unroll
        for (int oq = 0; oq < 8; ++oq) {
          float4 w = wb[oq];
          acc[oq*4+0].x = fmaf(w.x, xa, acc[oq*4+0].x); acc[oq*4+0].y = fmaf(w.x, xb, acc[oq*4+0].y);
          acc[oq*4+1].x = fmaf(w.y, xa, acc[oq*4+1].x); acc[oq*4+1].y = fmaf(w.y, xb, acc[oq*4+1].y);
          acc[oq*4+2].x = fmaf(w.z, xa, acc[oq*4+2].x); acc[oq*4+2].y = fmaf(w.z, xb, acc[oq*4+2].y);
          acc[oq*4+3].x = fmaf(w.w, xa, acc[oq*4+3].x); acc[oq*4+3].y = fmaf(w.w, xb, acc[oq*4+3].y);
        }
      }
    }
  }

  char* yp = ws + Y1T_OFF + ((size_t)(b * 130 + iy) * 132 + ix0) * 64;
  #pragma unroll
  for (int half = 0; half < 2; ++half) {
    uint32_t dd[16];
    #pragma unroll
    for (int o2 = 0; o2 < 16; ++o2)
      dd[o2] = half ? packbf(acc[2*o2].y, acc[2*o2+1].y) : packbf(acc[2*o2].x, acc[2*o2+1].x);
    #pragma unroll
    for (int k = 0; k < 4; ++k)
      *(uint4*)(yp + half * 64 + k * 16) = make_uint4(dd[4*k], dd[4*k+1], dd[4*k+2], dd[4*k+3]);
  }
}

// ---------------------------------------------------------------------------
// out0: one block per (b, jy); 4 waves x 4 px-frags = 256 px.
__global__ __launch_bounds__(256) void out0_k(const float* __restrict__ x0,
                                              const float* __restrict__ b0,
                                              const float* __restrict__ gg,
                                              const char* __restrict__ ws,
                                              float* __restrict__ out) {
  // x0s: ch-octet planes [ql 2][row 5][col 264][ch 8] bf16; col s <-> gx = s-2
  __shared__ __align__(16) uint16_t x0s[2 * 5 * 264 * 8];   // 42,240 B
  // y1s: planes [q 4][ry 2][col 132][ch 8] bf16; ry 0/1 <-> y1 rows uy+1/uy+2
  __shared__ __align__(16) uint16_t y1s[4 * 2 * 132 * 8];   // 16,896 B
  int tid = threadIdx.x;
  int b = blockIdx.x >> 8, jy = blockIdx.x & 255;

  { // stage x0 (fp32 -> bf16, transpose to [col][ch])
    const float* x0b = x0 + (size_t)b * 1048576;
    for (int e = tid; e < 5200; e += 256) {
      int r = e / 1040, rem = e % 1040;
      int cp = rem % 130, chp = rem / 130;
      int ch0 = chp * 2;
      int s0 = cp * 2;
      int gx0 = s0 - 2;
      int gy = jy + r - 2;
      float v00 = 0.f, v01 = 0.f, v10 = 0.f, v11 = 0.f;
      if ((unsigned)gy < 256u) {
        const float* r0 = x0b + (size_t)ch0 * 65536 + gy * 256;
        const float* r1 = r0 + 65536;
        if ((unsigned)gx0 < 256u)       { v00 = r0[gx0];     v10 = r1[gx0]; }
        if ((unsigned)(gx0 + 1) < 256u) { v01 = r0[gx0 + 1]; v11 = r1[gx0 + 1]; }
      }
      uint16_t* base = x0s + (ch0 >> 3) * 10560 + (r * 264 + s0) * 8 + (ch0 & 7);
      *(uint32_t*)base       = packbf(v00, v10);
      *(uint32_t*)(base + 8) = packbf(v01, v11);
    }
  }
  { // stage y1 rows uy+1, uy+2 (bf16 copy into planes)
    const char* y1tb = ws + Y1T_OFF;
    int uy = jy >> 1;
    for (int e = tid; e < 1040; e += 256) {
      int ry = e / 520, rem = e % 520;
      int c = rem >> 2, qq = rem & 3;
      short8 v = *(const short8*)(y1tb + ((size_t)(b * 130 + uy + 1 + ry) * 132 + c) * 64 + qq * 16);
      *(short8*)(y1s + qq * 2112 + (ry * 132 + c) * 8) = v;
    }
  }
  __syncthreads();

  int lane = tid & 63, wv = tid >> 6;
  int nn = lane & 15, q = lane >> 4, qh = q >> 1, ql = q & 1;
  const char* ab0 = ws + AB0_OFF;
  f32x4 acc[4];
  #pragma unroll
  for (int i = 0; i < 4; ++i) { acc[i][0]=0.f; acc[i][1]=0.f; acc[i][2]=0.f; acc[i][3]=0.f; }

  const uint16_t* xsl = x0s + ql * 10560;
  const uint16_t* ysl = y1s + q * 2112;
  int pxb = wv * 64 + nn;

  // --- G00 5x5 (center zeroed), tap-pair chunks ---
  #pragma unroll
  for (int c = 0; c < 13; ++c) {
    short8 A = *(const short8*)(ab0 + c * 1024 + lane * 16);
    const int tA = 2 * c;
    const int tB = (2 * c + 1 > 24) ? 24 : 2 * c + 1;
    const int offA = ((tA / 5) * 264 + (tA % 5)) * 8;
    const int offB = ((tB / 5) * 264 + (tB % 5)) * 8;
    int toff = qh ? offB : offA;
    const uint16_t* base = xsl + toff + pxb * 8;
    short8 B0 = *(const short8*)(base);
    short8 B1 = *(const short8*)(base + 128);
    short8 B2 = *(const short8*)(base + 256);
    short8 B3 = *(const short8*)(base + 384);
    acc[0] = mfma16(A, B0, acc[0]);
    acc[1] = mfma16(A, B1, acc[1]);
    acc[2] = mfma16(A, B2, acc[2]);
    acc[3] = mfma16(A, B3, acc[3]);
  }

  // --- T10^T(Y1): compact cols + parity masks; rows fixed by jy parity ---
  {
    const short8 z8 = {0,0,0,0,0,0,0,0};
    if ((jy & 1) == 0) {
      #pragma unroll
      for (int bx = 0; bx < 3; ++bx) {
        short8 A = *(const short8*)(ab0 + (16 + bx) * 1024 + lane * 16);
        bool keep = (((nn + 3 - bx) & 1) == 0);
        int cb = (nn + 3 - bx) >> 1;
        const uint16_t* base = ysl + (cb + wv * 32) * 8;   // ry = 0
        short8 B0 = *(const short8*)(base);
        short8 B1 = *(const short8*)(base + 64);
        short8 B2 = *(const short8*)(base + 128);
        short8 B3 = *(const short8*)(base + 192);
        if (!keep) { B0 = z8; B1 = z8; B2 = z8; B3 = z8; }
        acc[0] = mfma16(A, B0, acc[0]);
        acc[1] = mfma16(A, B1, acc[1]);
        acc[2] = mfma16(A, B2, acc[2]);
        acc[3] = mfma16(A, B3, acc[3]);
      }
    } else {
      #pragma unroll
      for (int s = 0; s < 2; ++s) {          // s=0: by=0 (ry=1); s=1: by=2 (ry=0)
        const int chunkb = s ? 19 : 13;
        const int rybase = s ? 0 : 1;
        #pragma unroll
        for (int bx = 0; bx < 3; ++bx) {
          short8 A = *(const short8*)(ab0 + (chunkb + bx) * 1024 + lane * 16);
          bool keep = (((nn + 3 - bx) & 1) == 0);
          int cb = (nn + 3 - bx) >> 1;
          const uint16_t* base = ysl + (rybase * 132 + cb + wv * 32) * 8;
          short8 B0 = *(const short8*)(base);
          short8 B1 = *(const short8*)(base + 64);
          short8 B2 = *(const short8*)(base + 128);
          short8 B3 = *(const short8*)(base + 192);
          if (!keep) { B0 = z8; B1 = z8; B2 = z8; B3 = z8; }
          acc[0] = mfma16(A, B0, acc[0]);
          acc[1] = mfma16(A, B1, acc[1]);
          acc[2] = mfma16(A, B2, acc[2]);
          acc[3] = mfma16(A, B3, acc[3]);
        }
      }
    }
  }

  // --- hollow center: -G10c[jy-parity][px-parity], column-parity masked ---
  {
    const short8 z8 = {0,0,0,0,0,0,0,0};
    short8 A = *(const short8*)(ab0 + (22 + (jy & 1)) * 1024 + lane * 16);
    const uint16_t* base = xsl + (2 * 264 + 2) * 8 + pxb * 8;
    short8 B0 = *(const short8*)(base);
    short8 B1 = *(const short8*)(base + 128);
    short8 B2 = *(const short8*)(base + 256);
    short8 B3 = *(const short8*)(base + 384);
    bool keep = ((nn & 1) == qh);     // k<16 rows multiply even px, k>=16 odd px
    if (!keep) { B0 = z8; B1 = z8; B2 = z8; B3 = z8; }
    acc[0] = mfma16(A, B0, acc[0]);
    acc[1] = mfma16(A, B1, acc[1]);
    acc[2] = mfma16(A, B2, acc[2]);
    acc[3] = mfma16(A, B3, acc[3]);
  }

  // --- epilogue: out = b0_hat*g0 - acc ---
  float rs0 = gg[0] / sqrtf(((const float*)(ws + SUM_OFF))[0]);
  #pragma unroll
  for (int i = 0; i < 4; ++i) {
    int px = wv * 64 + i * 16 + nn;
    #pragma unroll
    for (int reg = 0; reg < 4; ++reg) {
      int m = q * 4 + reg;
      size_t boff = ((size_t)m * 256 + jy) * 256 + px;
      out[((size_t)(b * 16 + m) * 256 + jy) * 256 + px] = b0[boff] * rs0 - acc[i][reg];
    }
  }
}

// ---------------------------------------------------------------------------
// out1: one block per (b, jy); 4 waves x 2 px-frags = 128 px; M=32 (2 blocks).
__global__ __launch_bounds__(256) void out1_k(const float* __restrict__ b1,
                                              const float* __restrict__ gg,
                                              const char* __restrict__ ws,
                                              float* __restrict__ out) {
  __shared__ __align__(16) uint16_t ys[4 * 3 * 132 * 8];   // 25,344 B
  __shared__ __align__(16) uint16_t x1s[4 * 128 * 8];      // 8,192 B
  int tid = threadIdx.x;
  int b = blockIdx.x >> 7, jy = blockIdx.x & 127;
  const char* y1tb = ws + Y1T_OFF;
  const char* x1tb = ws + X1T_OFF;
  for (int e = tid; e < 1584; e += 256) {
    int row = e / 528, rr = e % 528, c = rr >> 2, qq = rr & 3;
    short8 v = *(const short8*)(y1tb + ((size_t)(b * 130 + jy + row) * 132 + c) * 64 + qq * 16);
    *(short8*)(ys + qq * 3168 + (row * 132 + c) * 8) = v;
  }
  for (int e = tid; e < 512; e += 256) {
    int c = e >> 2, qq = e & 3;
    short8 v = *(const short8*)(x1tb + ((size_t)(b * 128 + jy) * 128 + c) * 64 + qq * 16);
    *(short8*)(x1s + qq * 1024 + c * 8) = v;
  }
  __syncthreads();

  int lane = tid & 63, wv = tid >> 6;
  int nn = lane & 15, q = lane >> 4;
  const char* ab1 = ws + AB1_OFF;
  f32x4 acc[2][2];
  #pragma unroll
  for (int i = 0; i < 2; ++i)
    #pragma unroll
    for (int h = 0; h < 2; ++h) { acc[i][h][0]=0.f; acc[i][h][1]=0.f; acc[i][h][2]=0.f; acc[i][h][3]=0.f; }

  const uint16_t* ysl = ys + q * 3168;
  const uint16_t* xsl = x1s + q * 1024;
  int pxb = wv * 32 + nn;

  #pragma unroll
  for (int t = 0; t < 9; ++t) {
    const int ay = t / 3, ax = t % 3;
    short8 A0 = *(const short8*)(ab1 + (t * 2 + 0) * 1024 + lane * 16);
    short8 A1 = *(const short8*)(ab1 + (t * 2 + 1) * 1024 + lane * 16);
    const uint16_t* base = ysl + ((2 - ay) * 132 + (2 - ax) + pxb) * 8;
    short8 B0 = *(const short8*)(base);
    short8 B1 = *(const short8*)(base + 128);
    acc[0][0] = mfma16(A0, B0, acc[0][0]);
    acc[0][1] = mfma16(A1, B0, acc[0][1]);
    acc[1][0] = mfma16(A0, B1, acc[1][0]);
    acc[1][1] = mfma16(A1, B1, acc[1][1]);
  }
  { // -sub1 blockdiag * x1
    short8 A0 = *(const short8*)(ab1 + 18 * 1024 + lane * 16);
    short8 A1 = *(const short8*)(ab1 + 19 * 1024 + lane * 16);
    const uint16_t* base = xsl + pxb * 8;
    short8 B0 = *(const short8*)(base);
    short8 B1 = *(const short8*)(base + 128);
    acc[0][0] = mfma16(A0, B0, acc[0][0]);
    acc[0][1] = mfma16(A1, B0, acc[0][1]);
    acc[1][0] = mfma16(A0, B1, acc[1][0]);
    acc[1][1] = mfma16(A1, B1, acc[1][1]);
  }

  float rs1 = gg[1] / sqrtf(((const float*)(ws + SUM_OFF))[1]);
  #pragma unroll
  for (int i = 0; i < 2; ++i) {
    int px = wv * 32 + i * 16 + nn;
    #pragma unroll
    for (int h = 0; h < 2; ++h)
      #pragma unroll
      for (int reg = 0; reg < 4; ++reg) {
        int m = h * 16 + q * 4 + reg;
        size_t boff = ((size_t)m * 128 + jy) * 128 + px;
        out[16777216 + ((size_t)(b * 32 + m) * 128 + jy) * 128 + px] = b1[boff] * rs1 - acc[i][h][reg];
      }
  }
}

// ---------------------------------------------------------------------------
extern "C" void kernel_launch(void* const* d_in, const int* in_sizes, int n_in,
                              void* d_out, int out_size, void* d_ws, size_t ws_size,
                              hipStream_t stream) {
  const float* x0  = (const float*)d_in[0];
  const float* x1  = (const float*)d_in[1];
  const float* W00 = (const float*)d_in[2];
  const float* W10 = (const float*)d_in[3];
  const float* W11 = (const float*)d_in[4];
  const float* b0  = (const float*)d_in[5];
  const float* b1  = (const float*)d_in[6];
  const float* g   = (const float*)d_in[7];
  float* out = (float*)d_out;
  char* ws   = (char*)d_ws;

  blob_k<<<88, 256, 0, stream>>>(W00, W10, W11, ws);
  sumsq_k<<<512, 256, 0, stream>>>(b0, 16 * 256 * 256, (float*)(ws + SUM_OFF));
  sumsq_k<<<512, 256, 0, stream>>>(b1, 32 * 128 * 128, (float*)(ws + SUM_OFF) + 1);
  x1t_k<<<2048, 256, 0, stream>>>(x1, ws);
  y1_kernel<<<(B_ * 130 * 65 + 511) / 512, 512, 0, stream>>>(x0, x1, W10, W11, ws);
  out0_k<<<4096, 256, 0, stream>>>(x0, b0, g, ws, out);
  out1_k<<<2048, 256, 0, stream>>>(b1, g, ws, out);
}